// Round 10
// baseline (548.149 us; speedup 1.0000x reference)
//
#include <hip/hip_runtime.h>
#include <stdint.h>

typedef __attribute__((ext_vector_type(8))) short short8;
typedef __attribute__((ext_vector_type(4))) float f32x4;
typedef __attribute__((ext_vector_type(4))) _Float16 h16x4;

#define LOG2E 1.4426950408889634f

// workspace layout (bytes) — ws ~1 GB, we use ~46.6 MB
#define OFF_WTT   0u          // W tiled bf16 [8][4][256][8]        = 131072
#define OFF_WHTB  131072u     // Wh tiled bf16 [256][4][256][8]     = 4194304
#define OFF_FSRC  12713984u   // f_src f32 [8192]
#define OFF_FDST  12746752u   // f_dst f32 [8192]
#define OFF_MKEY  12779520u   // max-key u32
#define OFF_LP    12779584u   // L partials f32 [8][8192]           = 262144
#define OFF_ACCH  13041728u   // ACC partials f16 [8][8192][256]    = 33554432

__device__ __forceinline__ unsigned short f2bf(float f) {
    union { float f; unsigned int i; } v; v.f = f;
    unsigned int u = v.i;
    return (unsigned short)((u + 0x7FFFu + ((u >> 16) & 1u)) >> 16);
}

// ---------------- K0: W (f32) -> tiled W^T (bf16), init max-key ----------------
__global__ void k0_init(const float* __restrict__ W,
                        unsigned short* __restrict__ WTt,
                        unsigned int* __restrict__ Mkey) {
    int idx = blockIdx.x * 256 + threadIdx.x;   // 65536 = i*256+o
    int i = idx >> 8, o = idx & 255;
    WTt[(i >> 5) * 8192 + ((i >> 3) & 3) * 2048 + o * 8 + (i & 7)] = f2bf(W[idx]);
    if (idx == 0) *Mkey = 0u;
}

// ---------------- K1: Wh = X@W, write tiled Wh (bf16), f_src/f_dst, global max ----
__global__ __launch_bounds__(256, 2)
void k1_stage1(const float* __restrict__ X,
               const unsigned short* __restrict__ WTt,
               const float* __restrict__ a_src,
               const float* __restrict__ a_dst,
               unsigned short* __restrict__ WhTb,
               float* __restrict__ f_src,
               float* __restrict__ f_dst,
               unsigned int* __restrict__ Mkey) {
    __shared__ __align__(16) unsigned short Bt[8192];   // 16 KB tile
    __shared__ float fsum[64];
    const int t = threadIdx.x, w = t >> 6, lane = t & 63, l15 = lane & 15, q = lane >> 4;
    const int rg = w & 1, cg = w >> 1;
    const int i0 = blockIdx.x * 32;
    const int arow = i0 + rg * 16 + l15;

    if (t < 64) fsum[t] = 0.f;

    float as[8], ad[8];
#pragma unroll
    for (int ci = 0; ci < 8; ++ci) {
        int col = cg * 128 + ci * 16 + l15;
        as[ci] = a_src[col]; ad[ci] = a_dst[col];
    }

    f32x4 acc[8];
#pragma unroll
    for (int ci = 0; ci < 8; ++ci) acc[ci] = (f32x4)0.f;

    for (int ks = 0; ks < 8; ++ks) {
        __syncthreads();
        {
            const uint4* src = (const uint4*)(WTt + ks * 8192);
            uint4* dst = (uint4*)Bt;
            dst[t] = src[t]; dst[256 + t] = src[256 + t];
            dst[512 + t] = src[512 + t]; dst[768 + t] = src[768 + t];
        }
        __syncthreads();
        const float* xp = X + (size_t)arow * 256 + ks * 32 + q * 8;
        float4 xa = *(const float4*)xp;
        float4 xb = *(const float4*)(xp + 4);
        short8 a;
        a[0] = (short)f2bf(xa.x); a[1] = (short)f2bf(xa.y);
        a[2] = (short)f2bf(xa.z); a[3] = (short)f2bf(xa.w);
        a[4] = (short)f2bf(xb.x); a[5] = (short)f2bf(xb.y);
        a[6] = (short)f2bf(xb.z); a[7] = (short)f2bf(xb.w);
#pragma unroll
        for (int ci = 0; ci < 8; ++ci) {
            short8 b = *(const short8*)((const char*)Bt + q * 4096 + (cg * 128 + ci * 16 + l15) * 16);
            acc[ci] = __builtin_amdgcn_mfma_f32_16x16x32_bf16(a, b, acc[ci], 0, 0, 0);
        }
    }

#pragma unroll
    for (int ci = 0; ci < 8; ++ci) {
        int col = cg * 128 + ci * 16 + l15;
        ushort4 v;
        v.x = f2bf(acc[ci][0]); v.y = f2bf(acc[ci][1]);
        v.z = f2bf(acc[ci][2]); v.w = f2bf(acc[ci][3]);
        size_t flat = (size_t)(i0 >> 5) * 8192 + (size_t)(rg * 2 + (q >> 1)) * 2048
                      + (size_t)col * 8 + (q & 1) * 4;
        *(ushort4*)(WhTb + flat) = v;
    }

#pragma unroll
    for (int reg = 0; reg < 4; ++reg) {
        float ps = 0.f, pd = 0.f;
#pragma unroll
        for (int ci = 0; ci < 8; ++ci) {
            ps += acc[ci][reg] * as[ci];
            pd += acc[ci][reg] * ad[ci];
        }
#pragma unroll
        for (int m = 1; m < 16; m <<= 1) {
            ps += __shfl_xor(ps, m, 64);
            pd += __shfl_xor(pd, m, 64);
        }
        if (l15 == 0) {
            atomicAdd(&fsum[rg * 16 + q * 4 + reg], ps);
            atomicAdd(&fsum[32 + rg * 16 + q * 4 + reg], pd);
        }
    }
    __syncthreads();
    if (t < 32) {
        int row = i0 + t;
        float ps = fsum[t], pd = fsum[32 + t];
        f_src[row] = ps;
        f_dst[row] = pd;
        union { float f; unsigned int u; } cv; cv.f = pd;
        unsigned int key = (cv.u & 0x80000000u) ? ~cv.u : (cv.u | 0x80000000u);
        atomicMax(Mkey, key);
    }
}

// ---------------- K2: barrier-free register-pipelined fused GAT ----------------
// grid (128 i-tiles x 8 j-chunks), 256 thr = 4 waves; wave = 16 rows x 256 cols.
// No LDS, no barriers. B-frags double-buffered in regs at distance-1 iter;
// adj/fd prefetched at distance-2 (unroll-2 => each parity half owns a gen buf).
// Every load's issue->use distance >= 1 full iteration => vmcnt never drains to 0.
__global__ __launch_bounds__(256, 2)
void k2_fused(const int* __restrict__ adj,
              const unsigned short* __restrict__ WhTb,
              const float* __restrict__ f_src,
              const float* __restrict__ f_dst,
              const unsigned int* __restrict__ Mkey,
              float* __restrict__ Lp,
              _Float16* __restrict__ ACCh) {
    const int t = threadIdx.x, w = t >> 6, lane = t & 63, l15 = lane & 15, q = lane >> 4;
    const int i0 = blockIdx.x * 64;
    const int jc = blockIdx.y;
    const int jb0 = jc * 1024;   // j base
    const int jw0 = jc * 32;     // 32-j tile base

    unsigned int key = *Mkey;
    union { unsigned int u; float f; } mv;
    mv.u = (key & 0x80000000u) ? (key & 0x7FFFFFFFu) : ~key;
    const float Mf = mv.f;
    const int rA = i0 + w * 16 + l15;
    const float fsA = f_src[rA];
    float vA = fsA + Mf; const float mcA = fmaxf(vA, 0.2f * vA) * LOG2E;

    const int* adjA = adj + (size_t)rA * 8192 + jb0 + q * 8;
    const float* fdp = f_dst + jb0 + q * 8;
    const unsigned short* Bbase = WhTb + (size_t)jw0 * 8192 + q * 2048 + l15 * 8;

    f32x4 acc[16];
#pragma unroll
    for (int ci = 0; ci < 16; ++ci) acc[ci] = (f32x4)0.f;
    float lsA = 0.f;

    // ---- prologue: B[0] -> bf0; adj/fd gen0=js0, gen1=js1 ----
    short8 bf0[16], bf1[16];
#pragma unroll
    for (int ci = 0; ci < 16; ++ci) bf0[ci] = *(const short8*)(Bbase + ci * 128);
    int4  a0_0 = *(const int4*)(adjA),        a0_1 = *(const int4*)(adjA + 4);
    float4 f0_0 = *(const float4*)(fdp),      f0_1 = *(const float4*)(fdp + 4);
    int4  a1_0 = *(const int4*)(adjA + 32),   a1_1 = *(const int4*)(adjA + 36);
    float4 f1_0 = *(const float4*)(fdp + 32), f1_1 = *(const float4*)(fdp + 36);

#pragma unroll 1
    for (int js2 = 0; js2 < 16; ++js2) {
        const int js = js2 * 2;
        // ================= even half: uses bf0, gen0 =================
        {
            const int jn = (js + 1) & 31;   // B for next half
            const unsigned short* bp = Bbase + (size_t)jn * 8192;
#pragma unroll
            for (int ci = 0; ci < 16; ++ci) bf1[ci] = *(const short8*)(bp + ci * 128);

            float fdv[8] = { f0_0.x, f0_0.y, f0_0.z, f0_0.w, f0_1.x, f0_1.y, f0_1.z, f0_1.w };
            int   aAv[8] = { a0_0.x, a0_0.y, a0_0.z, a0_0.w, a0_1.x, a0_1.y, a0_1.z, a0_1.w };
            short8 fragA;
#pragma unroll
            for (int k = 0; k < 8; ++k) {
                float tA = fsA + fdv[k];
                float eA = fmaxf(tA, 0.2f * tA);
                float pA = __builtin_amdgcn_exp2f(__builtin_fmaf(eA, LOG2E, -mcA));
                pA = (aAv[k] > 0) ? pA : 0.f;
                lsA += pA; fragA[k] = (short)f2bf(pA);
            }

            // refill gen0 with js+2 (distance-2)
            const int jp = (js + 2) & 31;
            a0_0 = *(const int4*)(adjA + jp * 32);
            a0_1 = *(const int4*)(adjA + jp * 32 + 4);
            f0_0 = *(const float4*)(fdp + jp * 32);
            f0_1 = *(const float4*)(fdp + jp * 32 + 4);

#pragma unroll
            for (int ci = 0; ci < 16; ++ci)
                acc[ci] = __builtin_amdgcn_mfma_f32_16x16x32_bf16(fragA, bf0[ci], acc[ci], 0, 0, 0);
        }
        // ================= odd half: uses bf1, gen1 =================
        {
            const int jn = (js + 2) & 31;   // B for next even half
            const unsigned short* bp = Bbase + (size_t)jn * 8192;
#pragma unroll
            for (int ci = 0; ci < 16; ++ci) bf0[ci] = *(const short8*)(bp + ci * 128);

            float fdv[8] = { f1_0.x, f1_0.y, f1_0.z, f1_0.w, f1_1.x, f1_1.y, f1_1.z, f1_1.w };
            int   aAv[8] = { a1_0.x, a1_0.y, a1_0.z, a1_0.w, a1_1.x, a1_1.y, a1_1.z, a1_1.w };
            short8 fragA;
#pragma unroll
            for (int k = 0; k < 8; ++k) {
                float tA = fsA + fdv[k];
                float eA = fmaxf(tA, 0.2f * tA);
                float pA = __builtin_amdgcn_exp2f(__builtin_fmaf(eA, LOG2E, -mcA));
                pA = (aAv[k] > 0) ? pA : 0.f;
                lsA += pA; fragA[k] = (short)f2bf(pA);
            }

            // refill gen1 with js+3 (distance-2)
            const int jp = (js + 3) & 31;
            a1_0 = *(const int4*)(adjA + jp * 32);
            a1_1 = *(const int4*)(adjA + jp * 32 + 4);
            f1_0 = *(const float4*)(fdp + jp * 32);
            f1_1 = *(const float4*)(fdp + jp * 32 + 4);

#pragma unroll
            for (int ci = 0; ci < 16; ++ci)
                acc[ci] = __builtin_amdgcn_mfma_f32_16x16x32_bf16(fragA, bf1[ci], acc[ci], 0, 0, 0);
        }
    }

    // row-sums: quads hold disjoint j; lanes 0-15 end with row totals
    lsA += __shfl_xor(lsA, 16, 64); lsA += __shfl_xor(lsA, 32, 64);
    if (lane < 16) Lp[(size_t)jc * 8192 + i0 + w * 16 + lane] = lsA;

    // f16 split-j partials; C/D layout row=q*4+reg, col=ci*16+l15
    _Float16* ap = ACCh + (size_t)jc * 2097152;
#pragma unroll
    for (int ci = 0; ci < 16; ++ci) {
#pragma unroll
        for (int reg = 0; reg < 4; ++reg) {
            int row = i0 + w * 16 + q * 4 + reg;
            ap[(size_t)row * 256 + ci * 16 + l15] = (_Float16)acc[ci][reg];
        }
    }
}

// ---------------- K4: combine 8 partials, normalize, elu, f32 out ----------------
__global__ void k4_final(const _Float16* __restrict__ ACCh,
                         const float* __restrict__ Lp,
                         float* __restrict__ out) {
    int gid = blockIdx.x * 256 + threadIdx.x;   // 524288 threads x 4 elems
    int i = gid >> 6;
    float s0 = 0.f, s1 = 0.f, s2 = 0.f, s3 = 0.f;
#pragma unroll
    for (int jc = 0; jc < 8; ++jc) {
        h16x4 v = *(const h16x4*)(ACCh + (size_t)jc * 2097152 + (size_t)gid * 4);
        s0 += (float)v[0]; s1 += (float)v[1]; s2 += (float)v[2]; s3 += (float)v[3];
    }
    float L = 0.f;
#pragma unroll
    for (int jc = 0; jc < 8; ++jc) L += Lp[jc * 8192 + i];
    float inv = (L > 0.f) ? (1.0f / L) : 0.f;
    float h0 = s0 * inv, h1 = s1 * inv, h2 = s2 * inv, h3 = s3 * inv;
    float4 o;
    o.x = (h0 > 0.f) ? h0 : expm1f(h0);
    o.y = (h1 > 0.f) ? h1 : expm1f(h1);
    o.z = (h2 > 0.f) ? h2 : expm1f(h2);
    o.w = (h3 > 0.f) ? h3 : expm1f(h3);
    *(float4*)(out + (size_t)gid * 4) = o;
}

extern "C" void kernel_launch(void* const* d_in, const int* in_sizes, int n_in,
                              void* d_out, int out_size, void* d_ws, size_t ws_size,
                              hipStream_t stream) {
    (void)in_sizes; (void)n_in; (void)out_size; (void)ws_size;
    const float* X   = (const float*)d_in[0];
    const int*   adj = (const int*)d_in[1];
    const float* W   = (const float*)d_in[2];
    const float* a_s = (const float*)d_in[3];
    const float* a_d = (const float*)d_in[4];

    char* ws = (char*)d_ws;
    unsigned short* WTt  = (unsigned short*)(ws + OFF_WTT);
    unsigned short* WhTb = (unsigned short*)(ws + OFF_WHTB);
    float*          fsrc = (float*)(ws + OFF_FSRC);
    float*          fdst = (float*)(ws + OFF_FDST);
    unsigned int*   Mkey = (unsigned int*)(ws + OFF_MKEY);
    float*          Lp   = (float*)(ws + OFF_LP);
    _Float16*       ACCh = (_Float16*)(ws + OFF_ACCH);
    float*          out  = (float*)d_out;

    k0_init<<<dim3(256), dim3(256), 0, stream>>>(W, WTt, Mkey);
    k1_stage1<<<dim3(256), dim3(256), 0, stream>>>(X, WTt, a_s, a_d, WhTb, fsrc, fdst, Mkey);
    k2_fused<<<dim3(128, 8), dim3(256), 0, stream>>>(adj, WhTb, fsrc, fdst, Mkey, Lp, ACCh);
    k4_final<<<dim3(2048), dim3(256), 0, stream>>>(ACCh, Lp, out);
}

// Round 11
// 467.494 us; speedup vs baseline: 1.1725x; 1.1725x over previous
//
#include <hip/hip_runtime.h>
#include <stdint.h>

typedef __attribute__((ext_vector_type(8))) short short8;
typedef __attribute__((ext_vector_type(4))) float f32x4;
typedef __attribute__((ext_vector_type(4))) _Float16 h16x4;

#define LOG2E 1.4426950408889634f

// workspace layout (bytes) — ws ~1 GB, we use ~30 MB
#define OFF_WTT   0u          // W tiled bf16 [8][4][256][8]        = 131072
#define OFF_WHTB  131072u     // Wh tiled bf16 [256][4][256][8]     = 4194304
#define OFF_FSRC  12713984u   // f_src f32 [8192]
#define OFF_FDST  12746752u   // f_dst f32 [8192]
#define OFF_MKEY  12779520u   // max-key u32
#define OFF_LP    12779584u   // L partials f32 [4][8192]           = 131072
#define OFF_ACCH  12910656u   // ACC partials f16 [4][8192][256]    = 16777216

__device__ __forceinline__ unsigned short f2bf(float f) {
    union { float f; unsigned int i; } v; v.f = f;
    unsigned int u = v.i;
    return (unsigned short)((u + 0x7FFFu + ((u >> 16) & 1u)) >> 16);
}

// async global->LDS DMA, 16 B per lane (global_load_lds_dwordx4).
__device__ __forceinline__ void stage16(const unsigned short* g, unsigned short* l) {
    __builtin_amdgcn_global_load_lds(
        (const __attribute__((address_space(1))) unsigned int*)g,
        (__attribute__((address_space(3))) unsigned int*)l,
        16, 0, 0);
}

// ---------------- K0: W (f32) -> tiled W^T (bf16), init max-key ----------------
__global__ void k0_init(const float* __restrict__ W,
                        unsigned short* __restrict__ WTt,
                        unsigned int* __restrict__ Mkey) {
    int idx = blockIdx.x * 256 + threadIdx.x;   // 65536 = i*256+o
    int i = idx >> 8, o = idx & 255;
    WTt[(i >> 5) * 8192 + ((i >> 3) & 3) * 2048 + o * 8 + (i & 7)] = f2bf(W[idx]);
    if (idx == 0) *Mkey = 0u;
}

// ---------------- K1: Wh = X@W, write tiled Wh (bf16), f_src/f_dst, global max ----
__global__ __launch_bounds__(256, 2)
void k1_stage1(const float* __restrict__ X,
               const unsigned short* __restrict__ WTt,
               const float* __restrict__ a_src,
               const float* __restrict__ a_dst,
               unsigned short* __restrict__ WhTb,
               float* __restrict__ f_src,
               float* __restrict__ f_dst,
               unsigned int* __restrict__ Mkey) {
    __shared__ __align__(16) unsigned short Bt[8192];   // 16 KB tile
    __shared__ float fsum[64];
    const int t = threadIdx.x, w = t >> 6, lane = t & 63, l15 = lane & 15, q = lane >> 4;
    const int rg = w & 1, cg = w >> 1;
    const int i0 = blockIdx.x * 32;
    const int arow = i0 + rg * 16 + l15;

    if (t < 64) fsum[t] = 0.f;

    float as[8], ad[8];
#pragma unroll
    for (int ci = 0; ci < 8; ++ci) {
        int col = cg * 128 + ci * 16 + l15;
        as[ci] = a_src[col]; ad[ci] = a_dst[col];
    }

    f32x4 acc[8];
#pragma unroll
    for (int ci = 0; ci < 8; ++ci) acc[ci] = (f32x4)0.f;

    for (int ks = 0; ks < 8; ++ks) {
        __syncthreads();
        {
            const uint4* src = (const uint4*)(WTt + ks * 8192);
            uint4* dst = (uint4*)Bt;
            dst[t] = src[t]; dst[256 + t] = src[256 + t];
            dst[512 + t] = src[512 + t]; dst[768 + t] = src[768 + t];
        }
        __syncthreads();
        const float* xp = X + (size_t)arow * 256 + ks * 32 + q * 8;
        float4 xa = *(const float4*)xp;
        float4 xb = *(const float4*)(xp + 4);
        short8 a;
        a[0] = (short)f2bf(xa.x); a[1] = (short)f2bf(xa.y);
        a[2] = (short)f2bf(xa.z); a[3] = (short)f2bf(xa.w);
        a[4] = (short)f2bf(xb.x); a[5] = (short)f2bf(xb.y);
        a[6] = (short)f2bf(xb.z); a[7] = (short)f2bf(xb.w);
#pragma unroll
        for (int ci = 0; ci < 8; ++ci) {
            short8 b = *(const short8*)((const char*)Bt + q * 4096 + (cg * 128 + ci * 16 + l15) * 16);
            acc[ci] = __builtin_amdgcn_mfma_f32_16x16x32_bf16(a, b, acc[ci], 0, 0, 0);
        }
    }

#pragma unroll
    for (int ci = 0; ci < 8; ++ci) {
        int col = cg * 128 + ci * 16 + l15;
        ushort4 v;
        v.x = f2bf(acc[ci][0]); v.y = f2bf(acc[ci][1]);
        v.z = f2bf(acc[ci][2]); v.w = f2bf(acc[ci][3]);
        size_t flat = (size_t)(i0 >> 5) * 8192 + (size_t)(rg * 2 + (q >> 1)) * 2048
                      + (size_t)col * 8 + (q & 1) * 4;
        *(ushort4*)(WhTb + flat) = v;
    }

#pragma unroll
    for (int reg = 0; reg < 4; ++reg) {
        float ps = 0.f, pd = 0.f;
#pragma unroll
        for (int ci = 0; ci < 8; ++ci) {
            ps += acc[ci][reg] * as[ci];
            pd += acc[ci][reg] * ad[ci];
        }
#pragma unroll
        for (int m = 1; m < 16; m <<= 1) {
            ps += __shfl_xor(ps, m, 64);
            pd += __shfl_xor(pd, m, 64);
        }
        if (l15 == 0) {
            atomicAdd(&fsum[rg * 16 + q * 4 + reg], ps);
            atomicAdd(&fsum[32 + rg * 16 + q * 4 + reg], pd);
        }
    }
    __syncthreads();
    if (t < 32) {
        int row = i0 + t;
        float ps = fsum[t], pd = fsum[32 + t];
        f_src[row] = ps;
        f_dst[row] = pd;
        union { float f; unsigned int u; } cv; cv.f = pd;
        unsigned int key = (cv.u & 0x80000000u) ? ~cv.u : (cv.u | 0x80000000u);
        atomicMax(Mkey, key);
    }
}

// ---------------- K2: fused GAT. adj ballot-packed in prologue (HBM once),
// inner loop touches only LDS + L2 B-tile DMA => barrier drains are cheap.
// grid (128 x 4), 512 thr = 8 waves: rg=w>>1 (16 rows), cg=w&1 (128 cols).
// 2 blocks/CU (57 KB LDS) = 16 waves/CU.
__global__ __launch_bounds__(512, 4)
void k2_fused(const int* __restrict__ adj,
              const unsigned short* __restrict__ WhTb,
              const float* __restrict__ f_src,
              const float* __restrict__ f_dst,
              const unsigned int* __restrict__ Mkey,
              float* __restrict__ Lp,
              _Float16* __restrict__ ACCh) {
    __shared__ __align__(16) unsigned short Bt[2][8192];   // 32 KB double buffer
    __shared__ unsigned int bits_s[64 * 65];               // 16.6 KB (pad 65)
    __shared__ float fd_s[2048];                           // 8 KB
    const int t = threadIdx.x, w = t >> 6, lane = t & 63, l15 = lane & 15, q = lane >> 4;
    const int rg = w >> 1, cg = w & 1;
    const int i0 = blockIdx.x * 64;
    const int jc = blockIdx.y;
    const int jb0 = jc * 2048;   // j base (2048 j per block)
    const int jw0 = jc * 64;     // 64 tiles of 32 j

    unsigned int key = *Mkey;
    union { unsigned int u; float f; } mv;
    mv.u = (key & 0x80000000u) ? (key & 0x7FFFFFFFu) : ~key;
    const float Mf = mv.f;
    const int rA = i0 + rg * 16 + l15;
    const float fsA = f_src[rA];
    float vA = fsA + Mf; const float mcA = fmaxf(vA, 0.2f * vA) * LOG2E;

    // ---- prologue: stage fd (2048 f32) ----
    { float4* d = (float4*)fd_s; d[t] = ((const float4*)(f_dst + jb0))[t]; }

    // ---- prologue: DMA B tile 0 into buf 0 (2 x 8 KB call-sites) ----
    {
        const unsigned short* gsrc = WhTb + (size_t)jw0 * 8192;
#pragma unroll
        for (int s = 0; s < 2; ++s)
            stage16(gsrc + s * 4096 + t * 8,
                    (unsigned short*)((char*)&Bt[0][0] + s * 8192 + w * 1024));
    }

    // ---- prologue: ballot-pack adjacency: wave packs rows w*8..w*8+7,
    // 32 chunks of 64 j each => 256 coalesced loads/wave, MLP 8 ----
    for (int g = 0; g < 32; ++g) {
        int v[8];
#pragma unroll
        for (int u = 0; u < 8; ++u) {
            int idx = g * 8 + u, r = idx >> 5, c = idx & 31;
            v[u] = adj[(size_t)(i0 + w * 8 + r) * 8192 + jb0 + c * 64 + lane];
        }
#pragma unroll
        for (int u = 0; u < 8; ++u) {
            int idx = g * 8 + u, r = idx >> 5, c = idx & 31;
            unsigned long long m = __ballot(v[u] > 0);
            if (lane == 0) {
                bits_s[(w * 8 + r) * 65 + 2 * c]     = (unsigned int)m;
                bits_s[(w * 8 + r) * 65 + 2 * c + 1] = (unsigned int)(m >> 32);
            }
        }
    }

    f32x4 acc[8];
#pragma unroll
    for (int ci = 0; ci < 8; ++ci) acc[ci] = (f32x4)0.f;
    float lsA = 0.f;
    __syncthreads();   // bits + fd + tile0 ready

    for (int js = 0; js < 64; ++js) {
        const int buf = js & 1;
        const int jn = (js + 1) & 63;   // wrap: harmless redundant restage

        // ---- DMA next tile into other buffer (L2-resident source) ----
        {
            const unsigned short* gsrc = WhTb + (size_t)(jw0 + jn) * 8192;
#pragma unroll
            for (int s = 0; s < 2; ++s)
                stage16(gsrc + s * 4096 + t * 8,
                        (unsigned short*)((char*)&Bt[buf ^ 1][0] + s * 8192 + w * 1024));
        }

        // ---- P fragment from LDS bits + fd: A[m=l15][k=q*8+j] ----
        unsigned int word = bits_s[(rg * 16 + l15) * 65 + js];
        unsigned int bA = word >> (q * 8);
        const float* fdp = fd_s + js * 32 + q * 8;
        float4 f0 = *(const float4*)fdp, f1 = *(const float4*)(fdp + 4);
        float fdv[8] = { f0.x, f0.y, f0.z, f0.w, f1.x, f1.y, f1.z, f1.w };
        short8 fragA;
#pragma unroll
        for (int k = 0; k < 8; ++k) {
            float tA = fsA + fdv[k];
            float eA = fmaxf(tA, 0.2f * tA);
            float pA = __builtin_amdgcn_exp2f(__builtin_fmaf(eA, LOG2E, -mcA));
            pA = ((bA >> k) & 1u) ? pA : 0.f;
            lsA += pA; fragA[k] = (short)f2bf(pA);
        }

        // ---- MFMA from current LDS buffer: wave's 128-col half ----
        const char* base = (const char*)&Bt[buf][0] + q * 4096 + (cg * 128 + l15) * 16;
#pragma unroll
        for (int ci = 0; ci < 8; ++ci) {
            short8 bf = *(const short8*)(base + ci * 256);
            acc[ci] = __builtin_amdgcn_mfma_f32_16x16x32_bf16(fragA, bf, acc[ci], 0, 0, 0);
        }

        __syncthreads();   // next tile ready; cheap drain (L2 DMA only)
    }

    // row-sums: quads hold disjoint j; cg=1 duplicates P => only cg=0 writes
    lsA += __shfl_xor(lsA, 16, 64); lsA += __shfl_xor(lsA, 32, 64);
    if (cg == 0 && lane < 16)
        Lp[(size_t)jc * 8192 + i0 + rg * 16 + lane] = lsA;

    // f16 split-j partials; C/D layout row=q*4+reg, col=ci*16+l15
    _Float16* ap = ACCh + (size_t)jc * 2097152;
#pragma unroll
    for (int ci = 0; ci < 8; ++ci) {
#pragma unroll
        for (int reg = 0; reg < 4; ++reg) {
            int row = i0 + rg * 16 + q * 4 + reg;
            ap[(size_t)row * 256 + cg * 128 + ci * 16 + l15] = (_Float16)acc[ci][reg];
        }
    }
}

// ---------------- K4: combine 4 partials, normalize, elu, f32 out ----------------
__global__ void k4_final(const _Float16* __restrict__ ACCh,
                         const float* __restrict__ Lp,
                         float* __restrict__ out) {
    int gid = blockIdx.x * 256 + threadIdx.x;   // 524288 threads x 4 elems
    int i = gid >> 6;
    float s0 = 0.f, s1 = 0.f, s2 = 0.f, s3 = 0.f;
#pragma unroll
    for (int jc = 0; jc < 4; ++jc) {
        h16x4 v = *(const h16x4*)(ACCh + (size_t)jc * 2097152 + (size_t)gid * 4);
        s0 += (float)v[0]; s1 += (float)v[1]; s2 += (float)v[2]; s3 += (float)v[3];
    }
    float L = 0.f;
#pragma unroll
    for (int jc = 0; jc < 4; ++jc) L += Lp[jc * 8192 + i];
    float inv = (L > 0.f) ? (1.0f / L) : 0.f;
    float h0 = s0 * inv, h1 = s1 * inv, h2 = s2 * inv, h3 = s3 * inv;
    float4 o;
    o.x = (h0 > 0.f) ? h0 : expm1f(h0);
    o.y = (h1 > 0.f) ? h1 : expm1f(h1);
    o.z = (h2 > 0.f) ? h2 : expm1f(h2);
    o.w = (h3 > 0.f) ? h3 : expm1f(h3);
    *(float4*)(out + (size_t)gid * 4) = o;
}

extern "C" void kernel_launch(void* const* d_in, const int* in_sizes, int n_in,
                              void* d_out, int out_size, void* d_ws, size_t ws_size,
                              hipStream_t stream) {
    (void)in_sizes; (void)n_in; (void)out_size; (void)ws_size;
    const float* X   = (const float*)d_in[0];
    const int*   adj = (const int*)d_in[1];
    const float* W   = (const float*)d_in[2];
    const float* a_s = (const float*)d_in[3];
    const float* a_d = (const float*)d_in[4];

    char* ws = (char*)d_ws;
    unsigned short* WTt  = (unsigned short*)(ws + OFF_WTT);
    unsigned short* WhTb = (unsigned short*)(ws + OFF_WHTB);
    float*          fsrc = (float*)(ws + OFF_FSRC);
    float*          fdst = (float*)(ws + OFF_FDST);
    unsigned int*   Mkey = (unsigned int*)(ws + OFF_MKEY);
    float*          Lp   = (float*)(ws + OFF_LP);
    _Float16*       ACCh = (_Float16*)(ws + OFF_ACCH);
    float*          out  = (float*)d_out;

    k0_init<<<dim3(256), dim3(256), 0, stream>>>(W, WTt, Mkey);
    k1_stage1<<<dim3(256), dim3(256), 0, stream>>>(X, WTt, a_s, a_d, WhTb, fsrc, fdst, Mkey);
    k2_fused<<<dim3(128, 4), dim3(512), 0, stream>>>(adj, WhTb, fsrc, fdst, Mkey, Lp, ACCh);
    k4_final<<<dim3(2048), dim3(256), 0, stream>>>(ACCh, Lp, out);
}